// Round 1
// baseline (328.918 us; speedup 1.0000x reference)
//
#include <hip/hip_runtime.h>

// Inverse Haar 2D wavelet: in (16,12,512,512) f32 -> out (16,3,1024,1024) f32
// in viewed as (BC=48 groups) x (4 subbands) x (512x512) planes.
// out[bc, 2h+0, 2w+0] = (A+Hh+V+D)*0.5
// out[bc, 2h+0, 2w+1] = (A+Hh-V-D)*0.5
// out[bc, 2h+1, 2w+0] = (A-Hh+V-D)*0.5
// out[bc, 2h+1, 2w+1] = (A-Hh-V+D)*0.5

__global__ __launch_bounds__(256) void
witlayer_iwt_kernel(const float* __restrict__ in, float* __restrict__ out) {
    constexpr int H = 512;
    constexpr int W = 512;
    constexpr int W4 = W / 4;                 // 128 float4 per row
    constexpr int PLANE = H * W;              // 262144
    constexpr int OUT_PLANE = (2 * H) * (2 * W); // 1048576

    const int tid = blockIdx.x * blockDim.x + threadIdx.x;
    // total threads = 48 * 512 * 128 = 3,145,728 ; exact multiple of grid*block
    const int w4 = tid & (W4 - 1);            // 7 bits
    const int h  = (tid >> 7) & (H - 1);      // 9 bits
    const int bc = tid >> 16;                 // 0..47

    const int in_base = h * W + w4 * 4;       // within a plane
    const float4* pA = (const float4*)(in + (size_t)(bc * 4 + 0) * PLANE + in_base);
    const float4* pH = (const float4*)(in + (size_t)(bc * 4 + 1) * PLANE + in_base);
    const float4* pV = (const float4*)(in + (size_t)(bc * 4 + 2) * PLANE + in_base);
    const float4* pD = (const float4*)(in + (size_t)(bc * 4 + 3) * PLANE + in_base);

    const float4 a  = *pA;
    const float4 hh = *pH;
    const float4 v  = *pV;
    const float4 d  = *pD;

    // butterfly, 4 columns at once
    float4 x00, x01, x10, x11;
    x00.x = (a.x + hh.x + v.x + d.x) * 0.5f;
    x01.x = (a.x + hh.x - v.x - d.x) * 0.5f;
    x10.x = (a.x - hh.x + v.x - d.x) * 0.5f;
    x11.x = (a.x - hh.x - v.x + d.x) * 0.5f;
    x00.y = (a.y + hh.y + v.y + d.y) * 0.5f;
    x01.y = (a.y + hh.y - v.y - d.y) * 0.5f;
    x10.y = (a.y - hh.y + v.y - d.y) * 0.5f;
    x11.y = (a.y - hh.y - v.y + d.y) * 0.5f;
    x00.z = (a.z + hh.z + v.z + d.z) * 0.5f;
    x01.z = (a.z + hh.z - v.z - d.z) * 0.5f;
    x10.z = (a.z - hh.z + v.z - d.z) * 0.5f;
    x11.z = (a.z - hh.z - v.z + d.z) * 0.5f;
    x00.w = (a.w + hh.w + v.w + d.w) * 0.5f;
    x01.w = (a.w + hh.w - v.w - d.w) * 0.5f;
    x10.w = (a.w - hh.w + v.w - d.w) * 0.5f;
    x11.w = (a.w - hh.w - v.w + d.w) * 0.5f;

    // interleave even/odd columns: row0 = [x00.x, x01.x, x00.y, x01.y | x00.z, x01.z, x00.w, x01.w]
    float* row0 = out + (size_t)bc * OUT_PLANE + (size_t)(2 * h) * (2 * W) + w4 * 8;
    float* row1 = row0 + 2 * W;

    float4 r0a = make_float4(x00.x, x01.x, x00.y, x01.y);
    float4 r0b = make_float4(x00.z, x01.z, x00.w, x01.w);
    float4 r1a = make_float4(x10.x, x11.x, x10.y, x11.y);
    float4 r1b = make_float4(x10.z, x11.z, x10.w, x11.w);

    ((float4*)row0)[0] = r0a;
    ((float4*)row0)[1] = r0b;
    ((float4*)row1)[0] = r1a;
    ((float4*)row1)[1] = r1b;
}

extern "C" void kernel_launch(void* const* d_in, const int* in_sizes, int n_in,
                              void* d_out, int out_size, void* d_ws, size_t ws_size,
                              hipStream_t stream) {
    const float* in = (const float*)d_in[0];
    float* out = (float*)d_out;
    // 48 * 512 * 128 threads, 256/block -> 12288 blocks
    const int total_threads = 48 * 512 * 128;
    const int block = 256;
    const int grid = total_threads / block;
    witlayer_iwt_kernel<<<grid, block, 0, stream>>>(in, out);
}

// Round 2
// 325.048 us; speedup vs baseline: 1.0119x; 1.0119x over previous
//
#include <hip/hip_runtime.h>

// Inverse Haar 2D wavelet: in (16,12,512,512) f32 -> out (16,3,1024,1024) f32
// in viewed as (BC=48 groups) x (4 subbands A,Hh,V,D) x (512x512) planes.
// out[bc, 2h+0, 2w+0] = (A+Hh+V+D)*0.5
// out[bc, 2h+0, 2w+1] = (A+Hh-V-D)*0.5
// out[bc, 2h+1, 2w+0] = (A-Hh+V-D)*0.5
// out[bc, 2h+1, 2w+1] = (A-Hh-V+D)*0.5
//
// R2 layout: one thread owns 2 input columns (float2 per plane) -> exactly one
// float4 per output row. Consecutive lanes write consecutive float4s: stores
// are fully wave-contiguous (1024 B per wave store instruction), loads are
// 8 B/lane contiguous (512 B/wave, full cache lines). Prior version's 16 B
// stores at 32 B stride half-filled 32 lines per instruction.

__global__ __launch_bounds__(256) void
witlayer_iwt_kernel(const float* __restrict__ in, float* __restrict__ out) {
    constexpr int W = 512;
    constexpr int W2 = W / 2;                    // 256 float2 per input row
    constexpr int PLANE = 512 * 512;             // 262144
    constexpr int OUT_PLANE = 1024 * 1024;       // 1048576
    constexpr int OUT_W = 1024;

    const int tid = blockIdx.x * blockDim.x + threadIdx.x;
    // total threads = 48 * 512 * 256 = 6,291,456
    const int f2 = tid & (W2 - 1);               // 8 bits: float2 index in row
    const int h  = (tid >> 8) & 511;             // 9 bits
    const int bc = tid >> 17;                    // 0..47

    const int in_off = h * W + f2 * 2;
    const float* base = in + (size_t)bc * 4 * PLANE + in_off;
    const float2 a  = *(const float2*)(base + 0 * PLANE);
    const float2 hh = *(const float2*)(base + 1 * PLANE);
    const float2 v  = *(const float2*)(base + 2 * PLANE);
    const float2 d  = *(const float2*)(base + 3 * PLANE);

    float4 r0, r1;
    r0.x = (a.x + hh.x + v.x + d.x) * 0.5f;
    r0.y = (a.x + hh.x - v.x - d.x) * 0.5f;
    r0.z = (a.y + hh.y + v.y + d.y) * 0.5f;
    r0.w = (a.y + hh.y - v.y - d.y) * 0.5f;
    r1.x = (a.x - hh.x + v.x - d.x) * 0.5f;
    r1.y = (a.x - hh.x - v.x + d.x) * 0.5f;
    r1.z = (a.y - hh.y + v.y - d.y) * 0.5f;
    r1.w = (a.y - hh.y - v.y + d.y) * 0.5f;

    float* orow = out + (size_t)bc * OUT_PLANE + (size_t)(2 * h) * OUT_W;
    ((float4*)orow)[f2] = r0;                    // row 2h
    ((float4*)(orow + OUT_W))[f2] = r1;          // row 2h+1
}

extern "C" void kernel_launch(void* const* d_in, const int* in_sizes, int n_in,
                              void* d_out, int out_size, void* d_ws, size_t ws_size,
                              hipStream_t stream) {
    const float* in = (const float*)d_in[0];
    float* out = (float*)d_out;
    const int total_threads = 48 * 512 * 256;    // 6,291,456
    const int block = 256;
    const int grid = total_threads / block;      // 24576
    witlayer_iwt_kernel<<<grid, block, 0, stream>>>(in, out);
}